// Round 1
// 194.062 us; speedup vs baseline: 1.0844x; 1.0844x over previous
//
#include <hip/hip_runtime.h>
#include <hip/hip_fp16.h>

typedef _Float16 half8_t __attribute__((ext_vector_type(8)));
typedef _Float16 half4_t __attribute__((ext_vector_type(4)));
typedef float f32x4 __attribute__((ext_vector_type(4)));

__device__ __forceinline__ void gload_lds16(const void* g, void* l) {
    __builtin_amdgcn_global_load_lds(
        (const __attribute__((address_space(1))) void*)g,
        (__attribute__((address_space(3))) void*)l,
        16, 0, 0);
}

#define SBAR() asm volatile("s_barrier" ::: "memory")

template <int N> __device__ __forceinline__ void vm_wait();
template <> __device__ __forceinline__ void vm_wait<0>() {
    asm volatile("s_waitcnt vmcnt(0)" ::: "memory");
}
template <> __device__ __forceinline__ void vm_wait<6>() {
    asm volatile("s_waitcnt vmcnt(6)" ::: "memory");
}

// ---------------- fused: PQ quantize (blocks [0,n_pq)) + x cast (rest) ----
// pq v7 (MFMA): scores S[cw][grp] = |c|^2 - 2 g.c via mfma_f32_16x16x32_f16.
// (unchanged from previous round — see history; 64 groups/block, top-2 + fp64
// near-tie fallback, exact vs fp32 reference semantics)
__global__ __launch_bounds__(256, 4) void pq_cvt_kernel(
    const float* __restrict__ W, const float* __restrict__ cbg,
    const float* __restrict__ rs, _Float16* __restrict__ wq,
    const float* __restrict__ x, _Float16* __restrict__ xh,
    int n_x, int groups_per_row, int n_pq_blocks) {
    __shared__ __align__(16) _Float16 cbh[256 * 8];  // fp16(-2c)
    __shared__ __align__(16) _Float16 cbl[256 * 8];  // fp16(-2c - cbh)
    __shared__ __align__(16) float    c2s[256];      // |c|^2
    __shared__ __align__(16) _Float16 ghb[64 * 8];   // fp16(g)
    __shared__ __align__(16) _Float16 glb[64 * 8];   // fp16(g - ghb)

    int tid = threadIdx.x;
    int bid = blockIdx.x;

    if (bid >= n_pq_blocks) {           // ---- cvt part ----
        int i = ((bid - n_pq_blocks) * 256 + tid) * 4;
        if (i < n_x) {
            float4 v = *(const float4*)(x + i);
            half4_t h;
            h[0] = (_Float16)v.x; h[1] = (_Float16)v.y;
            h[2] = (_Float16)v.z; h[3] = (_Float16)v.w;
            *(half4_t*)(xh + i) = h;
        }
        return;
    }

    // ---- pq part: this block owns 64 consecutive groups (one rs row chunk)
    int gblock = bid * 64;
    float rsv = rs[gblock / groups_per_row];   // uniform: 64 | groups_per_row
    float rinv = 1.0f / rsv;

    {   // stage codebook: thread k handles codeword k
        const float4* cp4 = (const float4*)(cbg + tid * 8);
        float4 ca = cp4[0], cb4 = cp4[1];
        float cv[8] = {ca.x, ca.y, ca.z, ca.w, cb4.x, cb4.y, cb4.z, cb4.w};
        float c2 = 0.0f;
#pragma unroll
        for (int i = 0; i < 8; i++) {
            float c = cv[i];
            c2 = fmaf(c, c, c2);
            float m = -2.0f * c;
            _Float16 h = (_Float16)m;
            cbh[tid * 8 + i] = h;
            cbl[tid * 8 + i] = (_Float16)(m - (float)h);
        }
        c2s[tid] = c2;
    }
    {   // stage this block's 64 groups (2 elems/thread, coalesced)
        const float* wp = W + (size_t)gblock * 8;
        float2 v2 = *(const float2*)(wp + tid * 2);
        float v0 = v2.x * rinv, v1 = v2.y * rinv;
        _Float16 h0 = (_Float16)v0, h1 = (_Float16)v1;
        ghb[tid * 2]     = h0;
        ghb[tid * 2 + 1] = h1;
        glb[tid * 2]     = (_Float16)(v0 - (float)h0);
        glb[tid * 2 + 1] = (_Float16)(v1 - (float)h1);
    }
    __syncthreads();

    int wave = tid >> 6, lane = tid & 63;
    int q = lane >> 4, n15 = lane & 15;

    // B-frag (groups): B[k=q*8+j][n] -> quads 0,1: gh ; quads 2,3: gl
    const _Float16* gsrc = (q < 2) ? ghb : glb;
    half8_t bfrag = *(const half8_t*)&gsrc[(wave * 16 + n15) * 8];

    // A-frag (codewords): A[m=n15][k=q*8+j] -> quads 0,2: ch ; 1,3: cl
    const _Float16* asrc = (q & 1) ? cbl : cbh;

    float best = 1e30f, sec = 1e30f;
    int bidx = 0, sidx = 0;
    int cw0 = q * 4;                    // this lane's codeword-row base

#pragma unroll 4
    for (int t = 0; t < 16; t++) {
        half8_t afrag = *(const half8_t*)&asrc[(t * 16 + n15) * 8];
        f32x4 cc = *(const f32x4*)&c2s[t * 16 + q * 4];
        f32x4 d = __builtin_amdgcn_mfma_f32_16x16x32_f16(afrag, bfrag, cc, 0, 0, 0);
#pragma unroll
        for (int r = 0; r < 4; r++) {
            float s = d[r];
            int cw = t * 16 + cw0 + r;
            bool lb = s < best;
            bool ls = s < sec;
            sidx = lb ? bidx : (ls ? cw : sidx);
            sec = __builtin_amdgcn_fmed3f(s, best, sec);
            bidx = lb ? cw : bidx;
            best = fminf(s, best);
        }
    }

    // merge the 4 quads (same group col, different codeword rows)
#pragma unroll
    for (int mstep = 0; mstep < 2; mstep++) {
        int mask = 16 << mstep;
        float ob = __shfl_xor(best, mask, 64);
        float os = __shfl_xor(sec, mask, 64);
        int obi = __shfl_xor(bidx, mask, 64);
        int osi = __shfl_xor(sidx, mask, 64);
        bool sw = ob < best;
        float nb = fminf(best, ob);
        int nbi = sw ? obi : bidx;
        float m1 = fmaxf(best, ob);     // loser of the firsts
        int m1i = sw ? bidx : obi;
        bool sw2 = os < sec;
        float m2 = fminf(sec, os);      // winner of the seconds
        int m2i = sw2 ? osi : sidx;
        bool sw3 = m2 < m1;
        best = nb; bidx = nbi;
        sec = fminf(m1, m2);
        sidx = sw3 ? m2i : m1i;
    }

    if (q == 0) {                        // lanes 0-15 finalize one group each
        int g = gblock + wave * 16 + n15;
        int bi = bidx;
        if (sec - best < 5e-4f) {
            // scaled fp64 compare: sum((w - rs*c)^2), ordering == original
            const float* wp = W + (size_t)g * 8;
            const float* cbp = cbg + bi * 8;
            const float* csp = cbg + sidx * 8;
            double rsd = (double)rsv;
            double db = 0.0, ds = 0.0;
#pragma unroll
            for (int i = 0; i < 8; i++) {
                double wd = (double)wp[i];
                double d1 = fma(-rsd, (double)cbp[i], wd);
                db = fma(d1, d1, db);
                double d2_ = fma(-rsd, (double)csp[i], wd);
                ds = fma(d2_, d2_, ds);
            }
            if (ds < db || (ds == db && sidx < bi)) bi = sidx;
        }
        const float* c = cbg + bi * 8;
        half8_t outv;
#pragma unroll
        for (int i = 0; i < 8; i++) outv[i] = (_Float16)(c[i] * rsv);
        *(half8_t*)(wq + (size_t)g * 8) = outv;
    }
}

// ---------------- GEMM: C[M][N] = A[M][K] @ B[N][K]^T (+ bias) ----------------
// 256x256 tile, BK=64, 8 waves (2Mx4N), 128 KiB LDS double-buffer,
// 4-phase schedule per K-tile with counted vmcnt(6) (never 0 in loop),
// XOR-swizzled LDS (linear gload_lds dest + inverse-swizzled global source),
// setprio(1) around MFMA clusters. Split-K via gridDim.z as before.
//
// Phase plan per K-tile kt (buf = kt&1):
//  P0: read A[m0-3]x2k (8) + B[n0-1]x2k (4); stage A1(kt+1)  -> 16 MFMA
//  P1: read B[n2-3]x2k (4)                                   -> 16 MFMA
//  P2: read A[m4-7]x2k (8); stage B0(kt+2) (B dead after P1) -> 16 MFMA
//  P3: stage B1(kt+2) + A0(kt+2) (A dead after P2)           -> 16 MFMA
//  boundary: vmcnt(6) (drains kt+1's 8 loads, keeps kt+2's 6 in flight)
// Steady-state invariant entering group kt: {B0,B1,A0 of kt+1} in flight.

// stage one 128-row x 64-col half-tile: linear LDS dest, source k-block
// pre-permuted by the read-side swizzle (slot ^ (row&7)).
__device__ __forceinline__ void stage_half(
    const _Float16* __restrict__ g, int K, int rowoff,
    _Float16* lt, int k0, int tid) {
#pragma unroll
    for (int l = 0; l < 2; ++l) {
        int u = l * 512 + tid;                 // 16B unit within half-tile
        int r = rowoff + (u >> 3);             // row in 256-row tile
        int ks = ((u & 7) ^ (r & 7)) << 3;     // source k offset (halfs)
        gload_lds16(g + (size_t)r * K + k0 + ks,
                    lt + (rowoff << 6) + ((l * 512 + (tid & ~63)) << 3));
    }
}

// swizzled LDS fragment read: element (r,k) lives at r*64 + (k ^ ((r&7)<<3))
__device__ __forceinline__ half8_t ldsr(const _Float16* t, int r, int k) {
    return *(const half8_t*)(t + r * 64 + (k ^ ((r & 7) << 3)));
}

__global__ __launch_bounds__(512, 2) void gemm_f16_256(
    const _Float16* __restrict__ A, const _Float16* __restrict__ B,
    const float* __restrict__ bias, float* __restrict__ C0,
    float* __restrict__ C1, int M, int N, int K, int Ksplit) {
    extern __shared__ __align__(16) _Float16 smem[];  // [2][A 16384 | B 16384]
    int tid = threadIdx.x;
    int wave = tid >> 6, lane = tid & 63;
    int wm = wave >> 2, wn = wave & 3;
    int l15 = lane & 15, q8 = (lane >> 4) * 8;
    int bn = blockIdx.x * 256, bm = blockIdx.y * 256;
    int kz = blockIdx.z;
    int kbase = kz * Ksplit;
    const _Float16* Ab = A + (size_t)bm * K;
    const _Float16* Bb = B + (size_t)bn * K;

    const int nkt = Ksplit / 64;
    f32x4 acc[8][4] = {};

    {   // prologue: kt0 fully + {B0,B1,A0} of kt1; drain kt0 (14 -> 6)
        _Float16* A0 = smem;
        _Float16* B0 = smem + 16384;
        _Float16* A1 = smem + 32768;
        _Float16* B1 = smem + 49152;
        stage_half(Ab, K, 0,   A0, kbase, tid);
        stage_half(Ab, K, 128, A0, kbase, tid);
        stage_half(Bb, K, 0,   B0, kbase, tid);
        stage_half(Bb, K, 128, B0, kbase, tid);
        asm volatile("" ::: "memory");   // keep kt0/kt1 issue order
        if (nkt > 1) {
            stage_half(Bb, K, 0,   B1, kbase + 64, tid);
            stage_half(Bb, K, 128, B1, kbase + 64, tid);
            stage_half(Ab, K, 0,   A1, kbase + 64, tid);
            vm_wait<6>();
        } else {
            vm_wait<0>();
        }
        SBAR();
    }

    for (int kt = 0; kt < nkt; ++kt) {
        _Float16* At = smem + (kt & 1) * 32768;
        _Float16* Bt = At + 16384;
        _Float16* Ao = smem + ((kt + 1) & 1) * 32768;  // other buffer (A)
        half8_t a[4][2], b[4][2];

        // ---- P0: A[m0-3], B[n0-1]; stage A1(kt+1) ----
#pragma unroll
        for (int mt = 0; mt < 4; mt++)
#pragma unroll
            for (int kk = 0; kk < 2; kk++)
                a[mt][kk] = ldsr(At, wm * 128 + mt * 16 + l15, kk * 32 + q8);
#pragma unroll
        for (int nt = 0; nt < 2; nt++)
#pragma unroll
            for (int kk = 0; kk < 2; kk++)
                b[nt][kk] = ldsr(Bt, wn * 64 + nt * 16 + l15, kk * 32 + q8);
        if (kt + 1 < nkt)
            stage_half(Ab, K, 128, Ao, kbase + (kt + 1) * 64, tid);
        SBAR();
        __builtin_amdgcn_s_setprio(1);
#pragma unroll
        for (int mt = 0; mt < 4; mt++)
#pragma unroll
            for (int nt = 0; nt < 2; nt++)
#pragma unroll
                for (int kk = 0; kk < 2; kk++)
                    acc[mt][nt] = __builtin_amdgcn_mfma_f32_16x16x32_f16(
                        a[mt][kk], b[nt][kk], acc[mt][nt], 0, 0, 0);
        __builtin_amdgcn_s_setprio(0);
        SBAR();

        // ---- P1: B[n2-3] ----
#pragma unroll
        for (int nt = 2; nt < 4; nt++)
#pragma unroll
            for (int kk = 0; kk < 2; kk++)
                b[nt][kk] = ldsr(Bt, wn * 64 + nt * 16 + l15, kk * 32 + q8);
        SBAR();
        __builtin_amdgcn_s_setprio(1);
#pragma unroll
        for (int mt = 0; mt < 4; mt++)
#pragma unroll
            for (int nt = 2; nt < 4; nt++)
#pragma unroll
                for (int kk = 0; kk < 2; kk++)
                    acc[mt][nt] = __builtin_amdgcn_mfma_f32_16x16x32_f16(
                        a[mt][kk], b[nt][kk], acc[mt][nt], 0, 0, 0);
        __builtin_amdgcn_s_setprio(0);
        SBAR();

        // ---- P2: A[m4-7]; stage B0(kt+2) over dead B rows 0-127 ----
#pragma unroll
        for (int mt = 0; mt < 4; mt++)
#pragma unroll
            for (int kk = 0; kk < 2; kk++)
                a[mt][kk] = ldsr(At, wm * 128 + 64 + mt * 16 + l15, kk * 32 + q8);
        if (kt + 2 < nkt)
            stage_half(Bb, K, 0, Bt, kbase + (kt + 2) * 64, tid);
        SBAR();
        __builtin_amdgcn_s_setprio(1);
#pragma unroll
        for (int mt = 0; mt < 4; mt++)
#pragma unroll
            for (int nt = 0; nt < 2; nt++)
#pragma unroll
                for (int kk = 0; kk < 2; kk++)
                    acc[4 + mt][nt] = __builtin_amdgcn_mfma_f32_16x16x32_f16(
                        a[mt][kk], b[nt][kk], acc[4 + mt][nt], 0, 0, 0);
        __builtin_amdgcn_s_setprio(0);
        SBAR();

        // ---- P3: stage B1(kt+2), A0(kt+2); MFMA from registers ----
        if (kt + 2 < nkt) {
            stage_half(Bb, K, 128, Bt, kbase + (kt + 2) * 64, tid);
            stage_half(Ab, K, 0,   At, kbase + (kt + 2) * 64, tid);
        }
        SBAR();
        __builtin_amdgcn_s_setprio(1);
#pragma unroll
        for (int mt = 0; mt < 4; mt++)
#pragma unroll
            for (int nt = 2; nt < 4; nt++)
#pragma unroll
                for (int kk = 0; kk < 2; kk++)
                    acc[4 + mt][nt] = __builtin_amdgcn_mfma_f32_16x16x32_f16(
                        a[mt][kk], b[nt][kk], acc[4 + mt][nt], 0, 0, 0);
        __builtin_amdgcn_s_setprio(0);
        // boundary: drain exactly kt+1's batch; keep kt+2's 6 in flight
        if (kt + 2 < nkt)      vm_wait<6>();
        else if (kt + 1 < nkt) vm_wait<0>();
        SBAR();
    }

    float* C = (kz == 0) ? C0 : C1;
    int col_base = bn + wn * 64;
    int row_base = bm + wm * 128;
#pragma unroll
    for (int nt = 0; nt < 4; nt++) {
        int col = col_base + nt * 16 + l15;
        float bv = (kz == 0) ? bias[col] : 0.0f;
#pragma unroll
        for (int mt = 0; mt < 8; mt++) {
            int r0 = row_base + mt * 16 + (lane >> 4) * 4;
#pragma unroll
            for (int r = 0; r < 4; r++)
                C[(size_t)(r0 + r) * N + col] = acc[mt][nt][r] + bv;
        }
    }
}

// ---------------- out += partial ----------------
__global__ __launch_bounds__(256) void reduce_add_kernel(
    float* __restrict__ out, const float* __restrict__ part, int n) {
    int i = (blockIdx.x * 256 + threadIdx.x) * 4;
    if (i < n) {
        float4 a = *(const float4*)(out + i);
        float4 b = *(const float4*)(part + i);
        a.x += b.x; a.y += b.y; a.z += b.z; a.w += b.w;
        *(float4*)(out + i) = a;
    }
}

extern "C" void kernel_launch(void* const* d_in, const int* in_sizes, int n_in,
                              void* d_out, int out_size, void* d_ws, size_t ws_size,
                              hipStream_t stream) {
    const float* x        = (const float*)d_in[0];
    const float* weight   = (const float*)d_in[1];
    const float* codebook = (const float*)d_in[2];
    const float* rowscale = (const float*)d_in[3];
    const float* bias     = (const float*)d_in[4];
    float* out = (float*)d_out;

    int O = in_sizes[3];          // row_scale has O elements
    int I = in_sizes[1] / O;      // weight is O*I
    int M = in_sizes[0] / I;      // x is (B*S)*I
    const int D = 8;
    int n_groups = O * I / D;

    size_t off = 0;
    _Float16* xh = (_Float16*)d_ws;                off += (size_t)M * I * sizeof(_Float16);
    _Float16* wq = (_Float16*)((char*)d_ws + off); off += (size_t)O * I * sizeof(_Float16);
    float* part = (float*)((char*)d_ws + off);
    size_t part_bytes = (size_t)M * O * sizeof(float);
    bool splitk = (ws_size >= off + part_bytes);

    static bool attr_set = false;
    if (!attr_set) {
        (void)hipFuncSetAttribute((const void*)gemm_f16_256,
                                  hipFuncAttributeMaxDynamicSharedMemorySize,
                                  131072);
        attr_set = true;
    }

    int n_x = M * I;
    int n_pq_blocks = n_groups / 64;
    int n_cvt_blocks = (n_x / 4 + 255) / 256;
    pq_cvt_kernel<<<n_pq_blocks + n_cvt_blocks, 256, 0, stream>>>(
        weight, codebook, rowscale, wq, x, xh, n_x, I / D, n_pq_blocks);

    if (splitk) {
        gemm_f16_256<<<dim3(O / 256, M / 256, 2), 512, 131072, stream>>>(
            xh, wq, bias, out, part, M, O, I, I / 2);
        reduce_add_kernel<<<(M * O / 4 + 255) / 256, 256, 0, stream>>>(
            out, part, M * O);
    } else {
        gemm_f16_256<<<dim3(O / 256, M / 256, 1), 512, 131072, stream>>>(
            xh, wq, bias, out, part, M, O, I, I);
    }
}

// Round 2
// 165.086 us; speedup vs baseline: 1.2747x; 1.1755x over previous
//
#include <hip/hip_runtime.h>
#include <hip/hip_fp16.h>

typedef _Float16 half8_t __attribute__((ext_vector_type(8)));
typedef _Float16 half4_t __attribute__((ext_vector_type(4)));
typedef float f32x4 __attribute__((ext_vector_type(4)));

__device__ __forceinline__ void gload_lds16(const void* g, void* l) {
    __builtin_amdgcn_global_load_lds(
        (const __attribute__((address_space(1))) void*)g,
        (__attribute__((address_space(3))) void*)l,
        16, 0, 0);
}

#define SBAR() asm volatile("s_barrier" ::: "memory")

template <int N> __device__ __forceinline__ void vm_wait();
template <> __device__ __forceinline__ void vm_wait<0>() {
    asm volatile("s_waitcnt vmcnt(0)" ::: "memory");
}
template <> __device__ __forceinline__ void vm_wait<4>() {
    asm volatile("s_waitcnt vmcnt(4)" ::: "memory");
}

// ---------------- fused: PQ quantize (blocks [0,n_pq)) + x cast (rest) ----
// pq v8: hot loop tracks (best, best_lc, sec_value) only = 4 VALU ops/score
// (cmp, literal-cndmask, med3, min). Second-best INDEX is recovered lazily:
// per-lane sidx enters the (unchanged) quad-merge as a sentinel -(q+1); if
// the final gap < 5e-4 and the winner is a sentinel, that lane recomputes
// its 16 MFMAs (LDS operands still resident -> bit-identical scores) and
// takes the first score == sec excluding its own best position — identical
// earliest-occurrence semantics to the old tracked sidx. fp64 fallback
// unchanged.
__global__ __launch_bounds__(256, 4) void pq_cvt_kernel(
    const float* __restrict__ W, const float* __restrict__ cbg,
    const float* __restrict__ rs, _Float16* __restrict__ wq,
    const float* __restrict__ x, _Float16* __restrict__ xh,
    int n_x, int groups_per_row, int n_pq_blocks) {
    __shared__ __align__(16) _Float16 cbh[256 * 8];  // fp16(-2c)
    __shared__ __align__(16) _Float16 cbl[256 * 8];  // fp16(-2c - cbh)
    __shared__ __align__(16) float    c2s[256];      // |c|^2
    __shared__ __align__(16) _Float16 ghb[64 * 8];   // fp16(g)
    __shared__ __align__(16) _Float16 glb[64 * 8];   // fp16(g - ghb)

    int tid = threadIdx.x;
    int bid = blockIdx.x;

    if (bid >= n_pq_blocks) {           // ---- cvt part ----
        int i = ((bid - n_pq_blocks) * 256 + tid) * 4;
        if (i < n_x) {
            float4 v = *(const float4*)(x + i);
            half4_t h;
            h[0] = (_Float16)v.x; h[1] = (_Float16)v.y;
            h[2] = (_Float16)v.z; h[3] = (_Float16)v.w;
            *(half4_t*)(xh + i) = h;
        }
        return;
    }

    // ---- pq part: this block owns 64 consecutive groups (one rs row chunk)
    int gblock = bid * 64;
    float rsv = rs[gblock / groups_per_row];   // uniform: 64 | groups_per_row
    float rinv = 1.0f / rsv;

    {   // stage codebook: thread k handles codeword k
        const float4* cp4 = (const float4*)(cbg + tid * 8);
        float4 ca = cp4[0], cb4 = cp4[1];
        float cv[8] = {ca.x, ca.y, ca.z, ca.w, cb4.x, cb4.y, cb4.z, cb4.w};
        float c2 = 0.0f;
#pragma unroll
        for (int i = 0; i < 8; i++) {
            float c = cv[i];
            c2 = fmaf(c, c, c2);
            float m = -2.0f * c;
            _Float16 h = (_Float16)m;
            cbh[tid * 8 + i] = h;
            cbl[tid * 8 + i] = (_Float16)(m - (float)h);
        }
        c2s[tid] = c2;
    }
    {   // stage this block's 64 groups (2 elems/thread, coalesced)
        const float* wp = W + (size_t)gblock * 8;
        float2 v2 = *(const float2*)(wp + tid * 2);
        float v0 = v2.x * rinv, v1 = v2.y * rinv;
        _Float16 h0 = (_Float16)v0, h1 = (_Float16)v1;
        ghb[tid * 2]     = h0;
        ghb[tid * 2 + 1] = h1;
        glb[tid * 2]     = (_Float16)(v0 - (float)h0);
        glb[tid * 2 + 1] = (_Float16)(v1 - (float)h1);
    }
    __syncthreads();

    int wave = tid >> 6, lane = tid & 63;
    int q = lane >> 4, n15 = lane & 15;

    // B-frag (groups): B[k=q*8+j][n] -> quads 0,1: gh ; quads 2,3: gl
    const _Float16* gsrc = (q < 2) ? ghb : glb;
    half8_t bfrag = *(const half8_t*)&gsrc[(wave * 16 + n15) * 8];

    // A-frag (codewords): A[m=n15][k=q*8+j] -> quads 0,2: ch ; 1,3: cl
    const _Float16* asrc = (q & 1) ? cbl : cbh;

    float best = 1e30f, sec = 1e30f;
    int blc = 0;                        // local code = t*16+r (compile-time lits)

#pragma unroll 4
    for (int t = 0; t < 16; t++) {
        half8_t afrag = *(const half8_t*)&asrc[(t * 16 + n15) * 8];
        f32x4 cc = *(const f32x4*)&c2s[t * 16 + q * 4];
        f32x4 d = __builtin_amdgcn_mfma_f32_16x16x32_f16(afrag, bfrag, cc, 0, 0, 0);
#pragma unroll
        for (int r = 0; r < 4; r++) {
            float s = d[r];
            bool lb = s < best;
            blc = lb ? (t * 16 + r) : blc;                     // literal cndmask
            sec = __builtin_amdgcn_fmed3f(s, best, sec);       // sec w/ OLD best
            best = fminf(s, best);
        }
    }
    int bidx = blc + q * 4;             // full codeword index
    int my_bidx = bidx;                 // pre-merge copy (rescan exclusion)
    int sidx = -(q + 1);                // sentinel: "lane q's local sec"

    // merge the 4 quads (same group col, different codeword rows) — verbatim
#pragma unroll
    for (int mstep = 0; mstep < 2; mstep++) {
        int mask = 16 << mstep;
        float ob = __shfl_xor(best, mask, 64);
        float os = __shfl_xor(sec, mask, 64);
        int obi = __shfl_xor(bidx, mask, 64);
        int osi = __shfl_xor(sidx, mask, 64);
        bool sw = ob < best;
        float nb = fminf(best, ob);
        int nbi = sw ? obi : bidx;
        float m1 = fmaxf(best, ob);     // loser of the firsts
        int m1i = sw ? bidx : obi;
        bool sw2 = os < sec;
        float m2 = fminf(sec, os);      // winner of the seconds
        int m2i = sw2 ? osi : sidx;
        bool sw3 = m2 < m1;
        best = nb; bidx = nbi;
        sec = fminf(m1, m2);
        sidx = sw3 ? m2i : m1i;
    }

    // broadcast q0's canonical merged result to the whole 4-lane clique
    // (on exact value ties the per-lane merge views can differ; q0 is canonical)
    float gbest = __shfl(best, n15, 64);
    float gsec  = __shfl(sec,  n15, 64);
    int   gbi   = __shfl(bidx, n15, 64);
    int   gsi   = __shfl(sidx, n15, 64);
    bool trig = (gsec - gbest < 5e-4f);

    if (trig && gsi < 0) {              // rare: recover second-best index
        int qs = -gsi - 1;
        int found = -1;
#pragma unroll 4
        for (int t = 0; t < 16; t++) {
            half8_t afrag = *(const half8_t*)&asrc[(t * 16 + n15) * 8];
            f32x4 cc = *(const f32x4*)&c2s[t * 16 + q * 4];
            f32x4 d = __builtin_amdgcn_mfma_f32_16x16x32_f16(afrag, bfrag, cc, 0, 0, 0);
#pragma unroll
            for (int r = 0; r < 4; r++) {
                int cw = t * 16 + q * 4 + r;
                if (q == qs && found < 0 && d[r] == gsec && cw != my_bidx)
                    found = cw;         // first (earliest) occurrence
            }
        }
        found = max(found, __shfl_xor(found, 16, 64));
        found = max(found, __shfl_xor(found, 32, 64));
        gsi = (found < 0) ? gbi : found;
    }

    if (q == 0) {                        // lanes 0-15 finalize one group each
        int g = gblock + wave * 16 + n15;
        int bi = gbi;
        if (trig) {
            // scaled fp64 compare: sum((w - rs*c)^2), ordering == original
            const float* wp = W + (size_t)g * 8;
            const float* cbp = cbg + bi * 8;
            const float* csp = cbg + gsi * 8;
            double rsd = (double)rsv;
            double db = 0.0, ds = 0.0;
#pragma unroll
            for (int i = 0; i < 8; i++) {
                double wd = (double)wp[i];
                double d1 = fma(-rsd, (double)cbp[i], wd);
                db = fma(d1, d1, db);
                double d2_ = fma(-rsd, (double)csp[i], wd);
                ds = fma(d2_, d2_, ds);
            }
            if (ds < db || (ds == db && gsi < bi)) bi = gsi;
        }
        const float* c = cbg + bi * 8;
        half8_t outv;
#pragma unroll
        for (int i = 0; i < 8; i++) outv[i] = (_Float16)(c[i] * rsv);
        *(half8_t*)(wq + (size_t)g * 8) = outv;
    }
}

// ---------------- GEMM: C[M][N] = A[M][K] @ B[N][K]^T (+ bias) ----------------
// 128(M) x 256(N) tile, BK=64, full K per block (NO split-K, no reduce pass):
// grid (N/256, M/128) = (8,32) = 256 blocks = 1/CU. 8 waves (2M x 4N), each
// 64x64. 96 KiB LDS double-buffer (A 16K + B 32K per buf). 4-phase schedule,
// counted vmcnt(4) at K-tile boundary (never 0 mid-loop), XOR-swizzled LDS
// (linear gload_lds dest + inverse-swizzled global source), setprio around
// MFMA clusters.
//
// Per K-tile kt (buf = kt&1), stage units: A(1), Blo, Bhi (2 loads/thread ea):
//  P0: read a[m0-1][kk*], b[n0-1][kk*]; stage A(kt+1)->other  -> 8 MFMA
//  P1: read a[m2-3], b[n2-3]                                  -> 8 MFMA
//  P2: stage Blo(kt+2) (rows 0-127 dead: all b reads done P1) -> 8 MFMA
//  P3: stage Bhi(kt+2)                                        -> 8 MFMA
//  boundary: vmcnt(4) — drains B(kt+1)+A(kt+1), keeps B(kt+2) in flight.
// Steady invariant entering kt: A(kt),B(kt) landed; B(kt+1) in flight.

__device__ __forceinline__ void stage_half(
    const _Float16* __restrict__ g, int K, int rowoff,
    _Float16* lt, int k0, int tid) {
#pragma unroll
    for (int l = 0; l < 2; ++l) {
        int u = l * 512 + tid;                 // 16B unit within half-tile
        int r = rowoff + (u >> 3);             // row in tile
        int ks = ((u & 7) ^ (r & 7)) << 3;     // source k offset (halfs)
        gload_lds16(g + (size_t)r * K + k0 + ks,
                    lt + (rowoff << 6) + ((l * 512 + (tid & ~63)) << 3));
    }
}

// swizzled LDS fragment read: element (r,k) lives at r*64 + (k ^ ((r&7)<<3))
__device__ __forceinline__ half8_t ldsr(const _Float16* t, int r, int k) {
    return *(const half8_t*)(t + r * 64 + (k ^ ((r & 7) << 3)));
}

__global__ __launch_bounds__(512, 2) void gemm_f16_mn(
    const _Float16* __restrict__ A, const _Float16* __restrict__ B,
    const float* __restrict__ bias, float* __restrict__ C,
    int M, int N, int K) {
    extern __shared__ __align__(16) _Float16 smem[];  // [2][A 8192 | B 16384]
    int tid = threadIdx.x;
    int wave = tid >> 6, lane = tid & 63;
    int wm = wave >> 2, wn = wave & 3;
    int l15 = lane & 15, q8 = (lane >> 4) * 8;
    int bn = blockIdx.x * 256, bm = blockIdx.y * 128;
    const _Float16* Ab = A + (size_t)bm * K;
    const _Float16* Bb = B + (size_t)bn * K;
    const int nkt = K / 64;

    f32x4 acc[4][4] = {};

    {   // prologue: A(0), Blo(0), Bhi(0), Blo(1), Bhi(1); drain first 6
        _Float16* A0 = smem;
        _Float16* B0 = smem + 8192;
        _Float16* B1 = smem + 24576 + 8192;
        stage_half(Ab, K, 0,   A0, 0, tid);
        stage_half(Bb, K, 0,   B0, 0, tid);
        stage_half(Bb, K, 128, B0, 0, tid);
        asm volatile("" ::: "memory");   // keep kt0/kt1 issue order
        if (nkt > 1) {
            stage_half(Bb, K, 0,   B1, 64, tid);
            stage_half(Bb, K, 128, B1, 64, tid);
            vm_wait<4>();
        } else {
            vm_wait<0>();
        }
        SBAR();
    }

    for (int kt = 0; kt < nkt; ++kt) {
        _Float16* At = smem + (kt & 1) * 24576;
        _Float16* Bt = At + 8192;
        _Float16* Ao = smem + ((kt + 1) & 1) * 24576;  // other buffer (A)
        int k1 = (kt + 1) * 64, k2 = (kt + 2) * 64;
        half8_t a[4][2], b[4][2];

        // ---- P0: a[m0-1], b[n0-1]; stage A(kt+1) ----
#pragma unroll
        for (int mt = 0; mt < 2; mt++)
#pragma unroll
            for (int kk = 0; kk < 2; kk++)
                a[mt][kk] = ldsr(At, wm * 64 + mt * 16 + l15, kk * 32 + q8);
#pragma unroll
        for (int nt = 0; nt < 2; nt++)
#pragma unroll
            for (int kk = 0; kk < 2; kk++)
                b[nt][kk] = ldsr(Bt, wn * 64 + nt * 16 + l15, kk * 32 + q8);
        if (kt + 1 < nkt)
            stage_half(Ab, K, 0, Ao, k1, tid);
        SBAR();
        __builtin_amdgcn_s_setprio(1);
#pragma unroll
        for (int mt = 0; mt < 2; mt++)
#pragma unroll
            for (int nt = 0; nt < 2; nt++)
#pragma unroll
                for (int kk = 0; kk < 2; kk++)
                    acc[mt][nt] = __builtin_amdgcn_mfma_f32_16x16x32_f16(
                        a[mt][kk], b[nt][kk], acc[mt][nt], 0, 0, 0);
        __builtin_amdgcn_s_setprio(0);
        SBAR();

        // ---- P1: a[m2-3], b[n2-3] ----
#pragma unroll
        for (int mt = 2; mt < 4; mt++)
#pragma unroll
            for (int kk = 0; kk < 2; kk++)
                a[mt][kk] = ldsr(At, wm * 64 + mt * 16 + l15, kk * 32 + q8);
#pragma unroll
        for (int nt = 2; nt < 4; nt++)
#pragma unroll
            for (int kk = 0; kk < 2; kk++)
                b[nt][kk] = ldsr(Bt, wn * 64 + nt * 16 + l15, kk * 32 + q8);
        SBAR();
        __builtin_amdgcn_s_setprio(1);
#pragma unroll
        for (int mt = 0; mt < 2; mt++)
#pragma unroll
            for (int nt = 2; nt < 4; nt++)
#pragma unroll
                for (int kk = 0; kk < 2; kk++)
                    acc[mt][nt] = __builtin_amdgcn_mfma_f32_16x16x32_f16(
                        a[mt][kk], b[nt][kk], acc[mt][nt], 0, 0, 0);
        __builtin_amdgcn_s_setprio(0);
        SBAR();

        // ---- P2: stage Blo(kt+2) over dead B rows 0-127 ----
        if (kt + 2 < nkt)
            stage_half(Bb, K, 0, Bt, k2, tid);
        SBAR();
        __builtin_amdgcn_s_setprio(1);
#pragma unroll
        for (int mt = 2; mt < 4; mt++)
#pragma unroll
            for (int nt = 0; nt < 2; nt++)
#pragma unroll
                for (int kk = 0; kk < 2; kk++)
                    acc[mt][nt] = __builtin_amdgcn_mfma_f32_16x16x32_f16(
                        a[mt][kk], b[nt][kk], acc[mt][nt], 0, 0, 0);
        __builtin_amdgcn_s_setprio(0);
        SBAR();

        // ---- P3: stage Bhi(kt+2); MFMA from registers; boundary wait ----
        if (kt + 2 < nkt)
            stage_half(Bb, K, 128, Bt, k2, tid);
        SBAR();
        __builtin_amdgcn_s_setprio(1);
#pragma unroll
        for (int mt = 2; mt < 4; mt++)
#pragma unroll
            for (int nt = 2; nt < 4; nt++)
#pragma unroll
                for (int kk = 0; kk < 2; kk++)
                    acc[mt][nt] = __builtin_amdgcn_mfma_f32_16x16x32_f16(
                        a[mt][kk], b[nt][kk], acc[mt][nt], 0, 0, 0);
        __builtin_amdgcn_s_setprio(0);
        if (kt + 2 < nkt)      vm_wait<4>();
        else if (kt + 1 < nkt) vm_wait<0>();
        SBAR();
    }

    int col_base = bn + wn * 64;
    int row_base = bm + wm * 64;
#pragma unroll
    for (int nt = 0; nt < 4; nt++) {
        int col = col_base + nt * 16 + l15;
        float bv = bias[col];
#pragma unroll
        for (int mt = 0; mt < 4; mt++) {
            int r0 = row_base + mt * 16 + (lane >> 4) * 4;
#pragma unroll
            for (int r = 0; r < 4; r++)
                C[(size_t)(r0 + r) * N + col] = acc[mt][nt][r] + bv;
        }
    }
}

extern "C" void kernel_launch(void* const* d_in, const int* in_sizes, int n_in,
                              void* d_out, int out_size, void* d_ws, size_t ws_size,
                              hipStream_t stream) {
    const float* x        = (const float*)d_in[0];
    const float* weight   = (const float*)d_in[1];
    const float* codebook = (const float*)d_in[2];
    const float* rowscale = (const float*)d_in[3];
    const float* bias     = (const float*)d_in[4];
    float* out = (float*)d_out;

    int O = in_sizes[3];          // row_scale has O elements
    int I = in_sizes[1] / O;      // weight is O*I
    int M = in_sizes[0] / I;      // x is (B*S)*I
    const int D = 8;
    int n_groups = O * I / D;

    size_t off = 0;
    _Float16* xh = (_Float16*)d_ws;                off += (size_t)M * I * sizeof(_Float16);
    _Float16* wq = (_Float16*)((char*)d_ws + off);

    static bool attr_set = false;
    if (!attr_set) {
        (void)hipFuncSetAttribute((const void*)gemm_f16_mn,
                                  hipFuncAttributeMaxDynamicSharedMemorySize,
                                  98304);
        attr_set = true;
    }

    int n_x = M * I;
    int n_pq_blocks = n_groups / 64;
    int n_cvt_blocks = (n_x / 4 + 255) / 256;
    pq_cvt_kernel<<<n_pq_blocks + n_cvt_blocks, 256, 0, stream>>>(
        weight, codebook, rowscale, wq, x, xh, n_x, I / D, n_pq_blocks);

    gemm_f16_mn<<<dim3(O / 256, M / 128), 512, 98304, stream>>>(
        xh, wq, bias, out, M, O, I);
}